// Round 7
// baseline (138.296 us; speedup 1.0000x reference)
//
#include <hip/hip_runtime.h>
#include <hip/hip_bf16.h>
#include <math.h>

// HGCN decoder, B=512, N=128, D=256, F=16, L=3, c=1 Poincare ball.
// 32x32x16 MFMA rebuild: 2 output tiles per wave in both GEMMs, A-frag
// reuse in GEMM-a (2 n-cols share one sT read), adj B-frags in registers
// for all 3 layers (one i-col per wave). Padded-linear LDS (stride % 32
// words == 4), cvt_pkrtz f16x4 epilogue stores. 16 waves / block.

typedef _Float16 f16;
typedef f16 f16x8 __attribute__((ext_vector_type(8)));
typedef f16 f16x4 __attribute__((ext_vector_type(4)));
typedef f16 f16x2 __attribute__((ext_vector_type(2)));
typedef __fp16 fp16x2_cv __attribute__((ext_vector_type(2)));
typedef float f32x4 __attribute__((ext_vector_type(4)));
typedef float f32x16 __attribute__((ext_vector_type(16)));

#define NB 512
#define NN 128
#define ND 256
#define NF 16
#define NL 3

#define SDT 264   // sT row stride f16: 528B = 132 words, %32 = 4
#define SDV 136   // sV row stride f16: 272B =  68 words, %32 = 4

#define EPSV   1e-7f
#define MAXN   0.99999f      // 1 - 1e-5
#define ATHMAX 6.1030340f    // atanh(1 - 1e-5)

__device__ __forceinline__ f16x4 pack4(float a, float b, float c, float d) {
    fp16x2_cv lo = __builtin_amdgcn_cvt_pkrtz(a, b);
    fp16x2_cv hi = __builtin_amdgcn_cvt_pkrtz(c, d);
    f16x2 lo2, hi2;
    __builtin_memcpy(&lo2, &lo, sizeof(lo2));
    __builtin_memcpy(&hi2, &hi, sizeof(hi2));
    return __builtin_shufflevector(lo2, hi2, 0, 1, 2, 3);
}

// One-time: Wt[l][n][k] = W[l][k][n] (f16), WoutT[f][k] = Wout[k][f] (f16).
__global__ void prep_kernel(const float* __restrict__ Ws,
                            const float* __restrict__ Wout,
                            f16* __restrict__ Wt, f16* __restrict__ WoutT) {
    int idx = blockIdx.x * 256 + threadIdx.x;
    if (idx < NL * ND * ND) {
        int l = idx / (ND * ND);
        int r = idx % (ND * ND);
        int n = r >> 8;
        int k = r & 255;
        Wt[idx] = (f16)Ws[l * ND * ND + k * ND + n];
    }
    if (idx < NF * ND) {
        int f = idx >> 8;
        int k = idx & 255;
        WoutT[idx] = (f16)Wout[k * NF + f];
    }
}

__global__ __launch_bounds__(1024, 4)
void hgcn_kernel(const float* __restrict__ x,
                 const float* __restrict__ adj,
                 const float* __restrict__ node_mask,
                 const f16*  __restrict__ Wt,
                 const float* __restrict__ bs,
                 const f16*  __restrict__ WoutT,
                 const float* __restrict__ bout,
                 float* __restrict__ out) {
    __shared__ __align__(16) f16 sT[NN * SDT];   // [node m][feat k] 66KB
    __shared__ __align__(16) f16 sV[ND * SDV];   // [feat n][node m] 68KB
    __shared__ __align__(16) float sRed[NN * 4]; // 4 partials per node 2KB

    const int b    = blockIdx.x;
    const int tid  = threadIdx.x;
    const int wave = tid >> 6;   // 0..15
    const int lane = tid & 63;
    const int l31  = lane & 31;
    const int hi   = lane >> 5;  // k-half for 32x32x16 fragments
    const int lg   = lane >> 4;  // head (16x16) only
    const int lc   = lane & 15;

    // GEMM-a roles: m-row mr (A reused across 2 n-cols {2*nc2, 2*nc2+1})
    const int mr  = wave >> 2;   // 0..3
    const int nc2 = wave & 3;    // 0..3
    // GEMM-b roles: i-col ic (adj frags), 2 n-tiles {2*nr2, 2*nr2+1}
    const int nr2 = wave >> 2;   // 0..3
    const int ic  = wave & 3;    // 0..3

    const f32x16 fzero16 = {0.f};

    // ---------- adj B-fragments (32 VGPRs, reused all 3 layers) ------------
    // GEMM-b MFMA B: B[col=i][k=j] = adj[i][j]; lane: i = ic*32+l31,
    // j = ks*16 + hi*8 .. +7.
    f16x8 adjf[8];
    {
        const float* adjb = adj + (size_t)b * NN * NN;
        #pragma unroll
        for (int ks = 0; ks < 8; ++ks) {
            const float4* ap = (const float4*)(adjb + (ic * 32 + l31) * NN + ks * 16 + hi * 8);
            float4 alo = ap[0], ahi = ap[1];
            f16x4 l4 = pack4(alo.x, alo.y, alo.z, alo.w);
            f16x4 h4 = pack4(ahi.x, ahi.y, ahi.z, ahi.w);
            adjf[ks] = __builtin_shufflevector(l4, h4, 0, 1, 2, 3, 4, 5, 6, 7);
        }
    }

    // ---------- init: sT = f16(logmap0(proj(x[b]))), 8 rows per wave -------
    {
        const float4* xb = (const float4*)(x + (size_t)b * NN * ND);
        #pragma unroll
        for (int r = 0; r < 8; ++r) {
            int row = wave * 8 + r;
            float4 v = xb[row * 64 + lane];
            float ssq = v.x * v.x + v.y * v.y + v.z * v.z + v.w * v.w;
            #pragma unroll
            for (int d = 1; d < 64; d <<= 1) ssq += __shfl_xor(ssq, d);
            float norm = sqrtf(ssq);
            float sc1 = (norm > MAXN) ? (MAXN / norm) : 1.0f;      // proj
            float hn  = fmaxf(norm * sc1, EPSV);
            float aa  = fminf(hn, MAXN);
            float ath = 0.5f * __logf((1.0f + aa) / (1.0f - aa));  // atanh
            float s   = sc1 * ath / hn;                            // logmap0
            *(f16x4*)&sT[row * SDT + lane * 4] =
                pack4(v.x * s, v.y * s, v.z * s, v.w * s);
        }
    }
    __syncthreads();

    for (int layer = 0; layer < NL; ++layer) {
        const f16* WtL = Wt + layer * ND * ND;

        // ---- GEMM-a: V[m][n] = T @ W + b.  2 tiles (mr, 2*nc2+t).
        // A = sT row (LDS, read once per ks, reused x2); B = Wt row (L2).
        f32x16 acc_a0 = fzero16, acc_a1 = fzero16;
        #pragma unroll
        for (int ks = 0; ks < 16; ++ks) {
            f16x8 afr = *(const f16x8*)&sT[(mr * 32 + l31) * SDT + ks * 16 + hi * 8];
            f16x8 b0 = *(const f16x8*)(WtL + ((2 * nc2 + 0) * 32 + l31) * ND + ks * 16 + hi * 8);
            f16x8 b1 = *(const f16x8*)(WtL + ((2 * nc2 + 1) * 32 + l31) * ND + ks * 16 + hi * 8);
            acc_a0 = __builtin_amdgcn_mfma_f32_32x32x16_f16(afr, b0, acc_a0, 0, 0, 0);
            acc_a1 = __builtin_amdgcn_mfma_f32_32x32x16_f16(afr, b1, acc_a1, 0, 0, 0);
        }
        // epilogue-a: +bias, pack f16x4 (4 consecutive m), store sV[n][m].
        {
            int n0 = (2 * nc2 + 0) * 32 + l31;
            int n1 = (2 * nc2 + 1) * 32 + l31;
            float bias0 = bs[layer * ND + n0];
            float bias1 = bs[layer * ND + n1];
            #pragma unroll
            for (int g = 0; g < 4; ++g) {
                int m0 = mr * 32 + 8 * g + 4 * hi;
                *(f16x4*)&sV[n0 * SDV + m0] =
                    pack4(acc_a0[4 * g + 0] + bias0, acc_a0[4 * g + 1] + bias0,
                          acc_a0[4 * g + 2] + bias0, acc_a0[4 * g + 3] + bias0);
                *(f16x4*)&sV[n1 * SDV + m0] =
                    pack4(acc_a1[4 * g + 0] + bias1, acc_a1[4 * g + 1] + bias1,
                          acc_a1[4 * g + 2] + bias1, acc_a1[4 * g + 3] + bias1);
            }
        }
        __syncthreads();

        // ---- GEMM-b: U^T[n][i] = sum_j V^T[n][j]*adj[i][j].
        // 2 tiles (2*nr2+t, ic). A = sV row n (LDS); B = adjf (registers).
        f32x16 acc_b0 = fzero16, acc_b1 = fzero16;
        #pragma unroll
        for (int ks = 0; ks < 8; ++ks) {
            f16x8 a0 = *(const f16x8*)&sV[((2 * nr2 + 0) * 32 + l31) * SDV + ks * 16 + hi * 8];
            f16x8 a1 = *(const f16x8*)&sV[((2 * nr2 + 1) * 32 + l31) * SDV + ks * 16 + hi * 8];
            acc_b0 = __builtin_amdgcn_mfma_f32_32x32x16_f16(a0, adjf[ks], acc_b0, 0, 0, 0);
            acc_b1 = __builtin_amdgcn_mfma_f32_32x32x16_f16(a1, adjf[ks], acc_b1, 0, 0, 0);
        }

        // ---- epilogue-b: relu + node-norm partials (this wave covers 64 of
        // 256 n for node i after the lane^32 fold; 4 waves share i-col).
        float ssq = 0.f;
        #pragma unroll
        for (int r = 0; r < 16; ++r) {
            float v0 = fmaxf(acc_b0[r], 0.0f);
            float v1 = fmaxf(acc_b1[r], 0.0f);
            acc_b0[r] = v0;
            acc_b1[r] = v1;
            ssq += v0 * v0 + v1 * v1;
        }
        ssq += __shfl_xor(ssq, 32);   // fold the two row-halves (same col i)
        if (lane < 32) sRed[(ic * 32 + l31) * 4 + nr2] = ssq;
        __syncthreads();

        f32x4 p = *(const f32x4*)&sRed[(ic * 32 + l31) * 4];
        float tot = p[0] + p[1] + p[2] + p[3];
        float nu = sqrtf(tot);
        float scale = (nu > ATHMAX) ? (ATHMAX / nu) : 1.0f;

        // fused logmap0(proj(expmap0(u))) = u * min(1, ATHMAX/||u||) -> sT.
        {
            int i = ic * 32 + l31;
            #pragma unroll
            for (int g = 0; g < 4; ++g) {
                int n0 = (2 * nr2 + 0) * 32 + 8 * g + 4 * hi;
                int n1 = (2 * nr2 + 1) * 32 + 8 * g + 4 * hi;
                *(f16x4*)&sT[i * SDT + n0] =
                    pack4(acc_b0[4 * g + 0] * scale, acc_b0[4 * g + 1] * scale,
                          acc_b0[4 * g + 2] * scale, acc_b0[4 * g + 3] * scale);
                *(f16x4*)&sT[i * SDT + n1] =
                    pack4(acc_b1[4 * g + 0] * scale, acc_b1[4 * g + 1] * scale,
                          acc_b1[4 * g + 2] * scale, acc_b1[4 * g + 3] * scale);
            }
        }
        __syncthreads();
    }

    // ---------- head: out = (out_tan @ Wout + bout) * node_mask ------------
    if (wave < 8) {
        f32x4 acc = {0.f, 0.f, 0.f, 0.f};
        #pragma unroll
        for (int ks = 0; ks < 8; ++ks) {
            f16x8 afr = *(const f16x8*)&sT[(wave * 16 + lc) * SDT + ks * 32 + lg * 8];
            f16x8 bfr = *(const f16x8*)(WoutT + lc * ND + ks * 32 + lg * 8);
            acc = __builtin_amdgcn_mfma_f32_16x16x32_f16(afr, bfr, acc, 0, 0, 0);
        }
        #pragma unroll
        for (int r = 0; r < 4; ++r) {
            int row = wave * 16 + lg * 4 + r;
            float mask = node_mask[b * NN + row];
            out[((size_t)b * NN + row) * NF + lc] = (acc[r] + bout[lc]) * mask;
        }
    }
}

extern "C" void kernel_launch(void* const* d_in, const int* in_sizes, int n_in,
                              void* d_out, int out_size, void* d_ws, size_t ws_size,
                              hipStream_t stream) {
    const float* x    = (const float*)d_in[0];
    const float* adj  = (const float*)d_in[1];
    const float* mask = (const float*)d_in[2];
    const float* Ws   = (const float*)d_in[3];
    const float* bsp  = (const float*)d_in[4];
    const float* Wout = (const float*)d_in[5];
    const float* bout = (const float*)d_in[6];

    f16* Wt    = (f16*)d_ws;                       // 3*256*256 f16 = 384KB
    f16* WoutT = Wt + NL * ND * ND;                // 16*256 f16 = 8KB

    prep_kernel<<<768, 256, 0, stream>>>(Ws, Wout, Wt, WoutT);
    hgcn_kernel<<<NB, 1024, 0, stream>>>(x, adj, mask, Wt, bsp, WoutT, bout,
                                         (float*)d_out);
}

// Round 8
// 99.814 us; speedup vs baseline: 1.3855x; 1.3855x over previous
//
#include <hip/hip_runtime.h>
#include <hip/hip_bf16.h>
#include <math.h>

// HGCN decoder, B=512, N=128, D=256, F=16, L=3, c=1 Poincare ball.
// Round-6 base (78us) with ONE change: GEMM-a rebuilt as 32x32x16 MFMA,
// (2 m-tiles x 1 n-col) per wave, with all 16 Wt B-fragments batch-preloaded
// into registers (2 batches of 8) so the inner loop is pure LDS+MFMA.
// GEMM-b / init / epilogues / head are round-6 verbatim.

typedef _Float16 f16;
typedef f16 f16x8 __attribute__((ext_vector_type(8)));
typedef f16 f16x4 __attribute__((ext_vector_type(4)));
typedef f16 f16x2 __attribute__((ext_vector_type(2)));
typedef __fp16 fp16x2_cv __attribute__((ext_vector_type(2)));
typedef float f32x4 __attribute__((ext_vector_type(4)));
typedef float f32x16 __attribute__((ext_vector_type(16)));

#define NB 512
#define NN 128
#define ND 256
#define NF 16
#define NL 3

#define SDT 264   // sT row stride f16: 528B = 132 words, %32 = 4
#define SDV 136   // sV row stride f16: 272B =  68 words, %32 = 4

#define EPSV   1e-7f
#define MAXN   0.99999f      // 1 - 1e-5
#define ATHMAX 6.1030340f    // atanh(1 - 1e-5)

__device__ __forceinline__ f16x4 pack4(float a, float b, float c, float d) {
    fp16x2_cv lo = __builtin_amdgcn_cvt_pkrtz(a, b);
    fp16x2_cv hi = __builtin_amdgcn_cvt_pkrtz(c, d);
    f16x2 lo2, hi2;
    __builtin_memcpy(&lo2, &lo, sizeof(lo2));
    __builtin_memcpy(&hi2, &hi, sizeof(hi2));
    return __builtin_shufflevector(lo2, hi2, 0, 1, 2, 3);
}

// One-time: Wt[l][n][k] = W[l][k][n] (f16), WoutT[f][k] = Wout[k][f] (f16).
__global__ void prep_kernel(const float* __restrict__ Ws,
                            const float* __restrict__ Wout,
                            f16* __restrict__ Wt, f16* __restrict__ WoutT) {
    int idx = blockIdx.x * 256 + threadIdx.x;
    if (idx < NL * ND * ND) {
        int l = idx / (ND * ND);
        int r = idx % (ND * ND);
        int n = r >> 8;
        int k = r & 255;
        Wt[idx] = (f16)Ws[l * ND * ND + k * ND + n];
    }
    if (idx < NF * ND) {
        int f = idx >> 8;
        int k = idx & 255;
        WoutT[idx] = (f16)Wout[k * NF + f];
    }
}

__global__ __launch_bounds__(1024, 4)
void hgcn_kernel(const float* __restrict__ x,
                 const float* __restrict__ adj,
                 const float* __restrict__ node_mask,
                 const f16*  __restrict__ Wt,
                 const float* __restrict__ bs,
                 const f16*  __restrict__ WoutT,
                 const float* __restrict__ bout,
                 float* __restrict__ out) {
    __shared__ __align__(16) f16 sT[NN * SDT];   // [node m][feat k] 66KB
    __shared__ __align__(16) f16 sV[ND * SDV];   // [feat n][node m] 68KB
    __shared__ float sRed[16 * 16];              // wave-pair norm exch 1KB

    const int b    = blockIdx.x;
    const int tid  = threadIdx.x;
    const int wave = tid >> 6;   // 0..15
    const int lane = tid & 63;
    const int l31  = lane & 31;
    const int hi   = lane >> 5;  // k-half for 32x32x16 fragments
    const int lg   = lane >> 4;  // 16x16 phases
    const int lc   = lane & 15;

    // GEMM-a roles (32x32): m-tiles {2*mr2, 2*mr2+1}, n-col nc.
    const int mr2 = wave & 1;    // 0..1
    const int nc  = wave >> 1;   // 0..7

    const f32x16 fzero16 = {0.f};

    // ---------- adj B-fragments (registers, reused all layers) -------------
    // GEMM-b: U^T[n][i] = sum_j V^T[n][j]*adj[i][j]; B[k=j][col=i], i-tile
    // = wave>>1 (wave pairs share an i-tile and split the n-range).
    f16x8 adjf[4];
    {
        const float* adjb = adj + (size_t)b * NN * NN;
        #pragma unroll
        for (int ks = 0; ks < 4; ++ks) {
            const float4* ap = (const float4*)(adjb + ((wave >> 1) * 16 + lc) * NN + ks * 32 + lg * 8);
            float4 alo = ap[0], ahi = ap[1];
            f16x4 l4 = pack4(alo.x, alo.y, alo.z, alo.w);
            f16x4 h4 = pack4(ahi.x, ahi.y, ahi.z, ahi.w);
            adjf[ks] = __builtin_shufflevector(l4, h4, 0, 1, 2, 3, 4, 5, 6, 7);
        }
    }

    // ---------- init: sT = f16(logmap0(proj(x[b]))), 8 rows per wave -------
    {
        const float4* xb = (const float4*)(x + (size_t)b * NN * ND);
        #pragma unroll
        for (int r = 0; r < 8; ++r) {
            int row = wave * 8 + r;
            float4 v = xb[row * 64 + lane];
            float ssq = v.x * v.x + v.y * v.y + v.z * v.z + v.w * v.w;
            #pragma unroll
            for (int d = 1; d < 64; d <<= 1) ssq += __shfl_xor(ssq, d);
            float norm = sqrtf(ssq);
            float sc1 = (norm > MAXN) ? (MAXN / norm) : 1.0f;      // proj
            float hn  = fmaxf(norm * sc1, EPSV);
            float aa  = fminf(hn, MAXN);
            float ath = 0.5f * __logf((1.0f + aa) / (1.0f - aa));  // atanh
            float s   = sc1 * ath / hn;                            // logmap0
            *(f16x4*)&sT[row * SDT + lane * 4] =
                pack4(v.x * s, v.y * s, v.z * s, v.w * s);
        }
    }
    __syncthreads();

    for (int layer = 0; layer < NL; ++layer) {
        const f16* WtL = Wt + layer * ND * ND;

        // ---- GEMM-a: V[m][n] = T @ W + b (32x32x16). Wave owns n-col nc
        // and m-tiles {2*mr2, 2*mr2+1}. All 16 B-frags (one Wt row per lane)
        // batch-preloaded into registers; ks loop is pure LDS+MFMA.
        f32x16 acc_a[2];
        acc_a[0] = fzero16;
        acc_a[1] = fzero16;

        const f16* wrow = WtL + (nc * 32 + l31) * ND + hi * 8;
        f16x8 bf0[8], bf1[8];
        #pragma unroll
        for (int k = 0; k < 8; ++k)
            bf0[k] = *(const f16x8*)(wrow + k * 16);
        #pragma unroll
        for (int k = 0; k < 8; ++k)
            bf1[k] = *(const f16x8*)(wrow + 128 + k * 16);
        __builtin_amdgcn_sched_barrier(0);

        #pragma unroll
        for (int ks = 0; ks < 8; ++ks) {
            f16x8 a0 = *(const f16x8*)&sT[(mr2 * 64 +      l31) * SDT + ks * 16 + hi * 8];
            f16x8 a1 = *(const f16x8*)&sT[(mr2 * 64 + 32 + l31) * SDT + ks * 16 + hi * 8];
            acc_a[0] = __builtin_amdgcn_mfma_f32_32x32x16_f16(a0, bf0[ks], acc_a[0], 0, 0, 0);
            acc_a[1] = __builtin_amdgcn_mfma_f32_32x32x16_f16(a1, bf0[ks], acc_a[1], 0, 0, 0);
        }
        #pragma unroll
        for (int ks = 0; ks < 8; ++ks) {
            f16x8 a0 = *(const f16x8*)&sT[(mr2 * 64 +      l31) * SDT + 128 + ks * 16 + hi * 8];
            f16x8 a1 = *(const f16x8*)&sT[(mr2 * 64 + 32 + l31) * SDT + 128 + ks * 16 + hi * 8];
            acc_a[0] = __builtin_amdgcn_mfma_f32_32x32x16_f16(a0, bf1[ks], acc_a[0], 0, 0, 0);
            acc_a[1] = __builtin_amdgcn_mfma_f32_32x32x16_f16(a1, bf1[ks], acc_a[1], 0, 0, 0);
        }

        // epilogue-a: +bias, pack f16x4 (4 consecutive m), store sV[n][m].
        {
            int n = nc * 32 + l31;
            float bias = bs[layer * ND + n];
            #pragma unroll
            for (int t = 0; t < 2; ++t)
                #pragma unroll
                for (int g = 0; g < 4; ++g) {
                    int m0 = (mr2 * 2 + t) * 32 + 8 * g + 4 * hi;
                    *(f16x4*)&sV[n * SDV + m0] =
                        pack4(acc_a[t][4 * g + 0] + bias, acc_a[t][4 * g + 1] + bias,
                              acc_a[t][4 * g + 2] + bias, acc_a[t][4 * g + 3] + bias);
                }
        }
        __syncthreads();

        // ---- GEMM-b: U^T[n][i] (16x16x32). i-tile = wave>>1, n-tiles
        // (wave&1)*8+nt. A = sV row n (LDS), B = adjf (registers).
        f32x4 acc_b[8];
        #pragma unroll
        for (int t = 0; t < 8; ++t) acc_b[t] = (f32x4){0.f, 0.f, 0.f, 0.f};

        #pragma unroll
        for (int ks = 0; ks < 4; ++ks) {
            #pragma unroll
            for (int nt = 0; nt < 8; ++nt) {
                f16x8 afr = *(const f16x8*)&sV[(((wave & 1) * 8 + nt) * 16 + lc) * SDV + ks * 32 + lg * 8];
                acc_b[nt] = __builtin_amdgcn_mfma_f32_16x16x32_f16(afr, adjf[ks], acc_b[nt], 0, 0, 0);
            }
        }

        // ---- epilogue-b: relu + half-node-norm; partner wave^1 has the
        // other n-half -> sRed exchange; fused rescale; write own sT rows.
        float ssq = 0.f;
        #pragma unroll
        for (int t = 0; t < 8; ++t)
            #pragma unroll
            for (int r = 0; r < 4; ++r) {
                float v = fmaxf(acc_b[t][r], 0.0f);
                acc_b[t][r] = v;
                ssq += v * v;
            }
        ssq += __shfl_xor(ssq, 16);   // reduce over lg lanes
        ssq += __shfl_xor(ssq, 32);
        if (lg == 0) sRed[wave * 16 + lc] = ssq;
        __syncthreads();
        float tot = ssq + sRed[(wave ^ 1) * 16 + lc];
        float nu = sqrtf(tot);
        float scale = (nu > ATHMAX) ? (ATHMAX / nu) : 1.0f;

        #pragma unroll
        for (int nt = 0; nt < 8; ++nt) {
            int i  = (wave >> 1) * 16 + lc;
            int k0 = ((wave & 1) * 8 + nt) * 16 + lg * 4;
            *(f16x4*)&sT[i * SDT + k0] =
                pack4(acc_b[nt][0] * scale, acc_b[nt][1] * scale,
                      acc_b[nt][2] * scale, acc_b[nt][3] * scale);
        }
        __syncthreads();
    }

    // ---------- head: out = (out_tan @ Wout + bout) * node_mask ------------
    if (wave < 8) {
        f32x4 acc = {0.f, 0.f, 0.f, 0.f};
        #pragma unroll
        for (int ks = 0; ks < 8; ++ks) {
            f16x8 afr = *(const f16x8*)&sT[(wave * 16 + lc) * SDT + ks * 32 + lg * 8];
            f16x8 bfr = *(const f16x8*)(WoutT + lc * ND + ks * 32 + lg * 8);
            acc = __builtin_amdgcn_mfma_f32_16x16x32_f16(afr, bfr, acc, 0, 0, 0);
        }
        #pragma unroll
        for (int r = 0; r < 4; ++r) {
            int row = wave * 16 + lg * 4 + r;
            float mask = node_mask[b * NN + row];
            out[((size_t)b * NN + row) * NF + lc] = (acc[r] + bout[lc]) * mask;
        }
    }
}

extern "C" void kernel_launch(void* const* d_in, const int* in_sizes, int n_in,
                              void* d_out, int out_size, void* d_ws, size_t ws_size,
                              hipStream_t stream) {
    const float* x    = (const float*)d_in[0];
    const float* adj  = (const float*)d_in[1];
    const float* mask = (const float*)d_in[2];
    const float* Ws   = (const float*)d_in[3];
    const float* bsp  = (const float*)d_in[4];
    const float* Wout = (const float*)d_in[5];
    const float* bout = (const float*)d_in[6];

    f16* Wt    = (f16*)d_ws;                       // 3*256*256 f16 = 384KB
    f16* WoutT = Wt + NL * ND * ND;                // 16*256 f16 = 8KB

    prep_kernel<<<768, 256, 0, stream>>>(Ws, Wout, Wt, WoutT);
    hgcn_kernel<<<NB, 1024, 0, stream>>>(x, adj, mask, Wt, bsp, WoutT, bout,
                                         (float*)d_out);
}

// Round 9
// 88.372 us; speedup vs baseline: 1.5649x; 1.1295x over previous
//
#include <hip/hip_runtime.h>
#include <hip/hip_bf16.h>
#include <math.h>

// HGCN decoder, B=512, N=128, D=256, F=16, L=3, c=1 Poincare ball.
// Round-6 base (78us) + (1) persistent Wt register fragments with
// cross-phase prefetch (layer L+1 loads issue under layer L's epilogues;
// layer-2 slot prefetches the head's WoutT), (2) GEMM-b as 32x32x16
// (R7-verified block: half the LDS reads and MFMA issue slots of 16x16).
// Padded-linear LDS (row stride % 32 words == 4), cvt_pkrtz f16x4 stores.

typedef _Float16 f16;
typedef f16 f16x8 __attribute__((ext_vector_type(8)));
typedef f16 f16x4 __attribute__((ext_vector_type(4)));
typedef f16 f16x2 __attribute__((ext_vector_type(2)));
typedef __fp16 fp16x2_cv __attribute__((ext_vector_type(2)));
typedef float f32x4 __attribute__((ext_vector_type(4)));
typedef float f32x16 __attribute__((ext_vector_type(16)));

#define NB 512
#define NN 128
#define ND 256
#define NF 16
#define NL 3

#define SDT 264   // sT row stride f16: 528B = 132 words, %32 = 4
#define SDV 136   // sV row stride f16: 272B =  68 words, %32 = 4

#define EPSV   1e-7f
#define MAXN   0.99999f      // 1 - 1e-5
#define ATHMAX 6.1030340f    // atanh(1 - 1e-5)

__device__ __forceinline__ f16x4 pack4(float a, float b, float c, float d) {
    fp16x2_cv lo = __builtin_amdgcn_cvt_pkrtz(a, b);
    fp16x2_cv hi = __builtin_amdgcn_cvt_pkrtz(c, d);
    f16x2 lo2, hi2;
    __builtin_memcpy(&lo2, &lo, sizeof(lo2));
    __builtin_memcpy(&hi2, &hi, sizeof(hi2));
    return __builtin_shufflevector(lo2, hi2, 0, 1, 2, 3);
}

// One-time: Wt[l][n][k] = W[l][k][n] (f16), WoutT[f][k] = Wout[k][f] (f16).
__global__ void prep_kernel(const float* __restrict__ Ws,
                            const float* __restrict__ Wout,
                            f16* __restrict__ Wt, f16* __restrict__ WoutT) {
    int idx = blockIdx.x * 256 + threadIdx.x;
    if (idx < NL * ND * ND) {
        int l = idx / (ND * ND);
        int r = idx % (ND * ND);
        int n = r >> 8;
        int k = r & 255;
        Wt[idx] = (f16)Ws[l * ND * ND + k * ND + n];
    }
    if (idx < NF * ND) {
        int f = idx >> 8;
        int k = idx & 255;
        WoutT[idx] = (f16)Wout[k * NF + f];
    }
}

__global__ __launch_bounds__(1024, 4)
void hgcn_kernel(const float* __restrict__ x,
                 const float* __restrict__ adj,
                 const float* __restrict__ node_mask,
                 const f16*  __restrict__ Wt,
                 const float* __restrict__ bs,
                 const f16*  __restrict__ WoutT,
                 const float* __restrict__ bout,
                 float* __restrict__ out) {
    __shared__ __align__(16) f16 sT[NN * SDT];   // [node m][feat k] 66KB
    __shared__ __align__(16) f16 sV[ND * SDV];   // [feat n][node m] 68KB
    __shared__ __align__(16) float sRed[NN * 4]; // 4 partials per node 2KB

    const int b    = blockIdx.x;
    const int tid  = threadIdx.x;
    const int wave = tid >> 6;   // 0..15
    const int lane = tid & 63;
    const int l31  = lane & 31;
    const int hi   = lane >> 5;  // k-half for 32x32x16 fragments
    const int lg   = lane >> 4;  // 16x16 phases
    const int lc   = lane & 15;

    // GEMM-b roles (32x32): i-col ic, n-tile pair {2*nr2, 2*nr2+1}
    const int nr2 = wave >> 2;   // 0..3
    const int ic  = wave & 3;    // 0..3

    const f32x16 fzero16 = {0.f};

    // ---------- adj B-fragments (32 VGPR, reused all 3 layers) -------------
    // GEMM-b: U^T[n][i] = sum_j V^T[n][j]*adj[i][j]; B[k=j][col=i] =
    // adj[ic*32+l31][j], j = ks*16 + hi*8 .. +7.
    f16x8 adjf[8];
    {
        const float* adjb = adj + (size_t)b * NN * NN;
        #pragma unroll
        for (int ks = 0; ks < 8; ++ks) {
            const float4* ap = (const float4*)(adjb + (ic * 32 + l31) * NN + ks * 16 + hi * 8);
            float4 alo = ap[0], ahi = ap[1];
            f16x4 l4 = pack4(alo.x, alo.y, alo.z, alo.w);
            f16x4 h4 = pack4(ahi.x, ahi.y, ahi.z, ahi.w);
            adjf[ks] = __builtin_shufflevector(l4, h4, 0, 1, 2, 3, 4, 5, 6, 7);
        }
    }

    // ---------- Wt fragments, layer 0 (issue before init; consume after) ---
    // GEMM-a B: B[col=n][k]: n = wave*16+lc, k = ks*32 + lg*8 .. +7.
    const f16* wbase = Wt + (wave * 16 + lc) * ND + lg * 8;
    f16x8 wreg[8];
    #pragma unroll
    for (int k = 0; k < 8; ++k)
        wreg[k] = *(const f16x8*)(wbase + k * 32);

    // ---------- init: sT = f16(logmap0(proj(x[b]))), 8 rows per wave -------
    {
        const float4* xb = (const float4*)(x + (size_t)b * NN * ND);
        #pragma unroll
        for (int r = 0; r < 8; ++r) {
            int row = wave * 8 + r;
            float4 v = xb[row * 64 + lane];
            float ssq = v.x * v.x + v.y * v.y + v.z * v.z + v.w * v.w;
            #pragma unroll
            for (int d = 1; d < 64; d <<= 1) ssq += __shfl_xor(ssq, d);
            float norm = sqrtf(ssq);
            float sc1 = (norm > MAXN) ? (MAXN / norm) : 1.0f;      // proj
            float hn  = fmaxf(norm * sc1, EPSV);
            float aa  = fminf(hn, MAXN);
            float ath = 0.5f * __logf((1.0f + aa) / (1.0f - aa));  // atanh
            float s   = sc1 * ath / hn;                            // logmap0
            *(f16x4*)&sT[row * SDT + lane * 4] =
                pack4(v.x * s, v.y * s, v.z * s, v.w * s);
        }
    }
    __syncthreads();

    for (int layer = 0; layer < NL; ++layer) {
        const float bias = bs[layer * ND + wave * 16 + lc];  // n = wave*16+lc

        // ---- GEMM-a: V[m][n] = T @ W + b (16x16x32). Wave owns n-tile =
        // wave, all 8 m-tiles. A = sT row m (LDS), B = wreg (registers,
        // prefetched). Pure LDS+MFMA inner loop.
        f32x4 acc_a[8];
        #pragma unroll
        for (int t = 0; t < 8; ++t) acc_a[t] = (f32x4){0.f, 0.f, 0.f, 0.f};

        #pragma unroll
        for (int ks = 0; ks < 8; ++ks) {
            f16x8 bfr = wreg[ks];
            #pragma unroll
            for (int mt = 0; mt < 8; ++mt) {
                f16x8 afr = *(const f16x8*)&sT[(mt * 16 + lc) * SDT + ks * 32 + lg * 8];
                acc_a[mt] = __builtin_amdgcn_mfma_f32_16x16x32_f16(afr, bfr, acc_a[mt], 0, 0, 0);
            }
        }

        // ---- prefetch next phase's B fragments (hidden under epilogues,
        // GEMM-b, and the intervening barriers). Layer 2 slot = head WoutT.
        if (layer + 1 < NL) {
            const f16* wn = wbase + (layer + 1) * ND * ND;
            #pragma unroll
            for (int k = 0; k < 8; ++k)
                wreg[k] = *(const f16x8*)(wn + k * 32);
        } else {
            const f16* wn = WoutT + lc * ND + lg * 8;
            #pragma unroll
            for (int k = 0; k < 8; ++k)
                wreg[k] = *(const f16x8*)(wn + k * 32);
        }

        // epilogue-a: +bias, pack f16x4 (4 consecutive m), store sV[n][m].
        #pragma unroll
        for (int mt = 0; mt < 8; ++mt) {
            int n  = wave * 16 + lc;
            int m0 = mt * 16 + lg * 4;
            *(f16x4*)&sV[n * SDV + m0] =
                pack4(acc_a[mt][0] + bias, acc_a[mt][1] + bias,
                      acc_a[mt][2] + bias, acc_a[mt][3] + bias);
        }
        __syncthreads();

        // ---- GEMM-b: U^T[n][i] (32x32x16). 2 n-tiles {2*nr2+t} x i-col ic.
        // A = sV row n (LDS), B = adjf (registers).
        f32x16 acc_b0 = fzero16, acc_b1 = fzero16;
        #pragma unroll
        for (int ks = 0; ks < 8; ++ks) {
            f16x8 a0 = *(const f16x8*)&sV[((2 * nr2 + 0) * 32 + l31) * SDV + ks * 16 + hi * 8];
            f16x8 a1 = *(const f16x8*)&sV[((2 * nr2 + 1) * 32 + l31) * SDV + ks * 16 + hi * 8];
            acc_b0 = __builtin_amdgcn_mfma_f32_32x32x16_f16(a0, adjf[ks], acc_b0, 0, 0, 0);
            acc_b1 = __builtin_amdgcn_mfma_f32_32x32x16_f16(a1, adjf[ks], acc_b1, 0, 0, 0);
        }

        // ---- epilogue-b: relu + node-norm partials (wave covers 64 of 256
        // n for node i after the lane^32 fold; 4 waves share i-col).
        float ssq = 0.f;
        #pragma unroll
        for (int r = 0; r < 16; ++r) {
            float v0 = fmaxf(acc_b0[r], 0.0f);
            float v1 = fmaxf(acc_b1[r], 0.0f);
            acc_b0[r] = v0;
            acc_b1[r] = v1;
            ssq += v0 * v0 + v1 * v1;
        }
        ssq += __shfl_xor(ssq, 32);   // fold the two row-halves (same col i)
        if (lane < 32) sRed[(ic * 32 + l31) * 4 + nr2] = ssq;
        __syncthreads();

        f32x4 p = *(const f32x4*)&sRed[(ic * 32 + l31) * 4];
        float tot = p[0] + p[1] + p[2] + p[3];
        float nu = sqrtf(tot);
        float scale = (nu > ATHMAX) ? (ATHMAX / nu) : 1.0f;

        // fused logmap0(proj(expmap0(u))) = u * min(1, ATHMAX/||u||) -> sT.
        {
            int i = ic * 32 + l31;
            #pragma unroll
            for (int g = 0; g < 4; ++g) {
                int n0 = (2 * nr2 + 0) * 32 + 8 * g + 4 * hi;
                int n1 = (2 * nr2 + 1) * 32 + 8 * g + 4 * hi;
                *(f16x4*)&sT[i * SDT + n0] =
                    pack4(acc_b0[4 * g + 0] * scale, acc_b0[4 * g + 1] * scale,
                          acc_b0[4 * g + 2] * scale, acc_b0[4 * g + 3] * scale);
                *(f16x4*)&sT[i * SDT + n1] =
                    pack4(acc_b1[4 * g + 0] * scale, acc_b1[4 * g + 1] * scale,
                          acc_b1[4 * g + 2] * scale, acc_b1[4 * g + 3] * scale);
            }
        }
        __syncthreads();
    }

    // ---------- head: out = (out_tan @ Wout + bout) * node_mask ------------
    // B fragments already in wreg (prefetched from WoutT during layer 2).
    if (wave < 8) {
        f32x4 acc = {0.f, 0.f, 0.f, 0.f};
        #pragma unroll
        for (int ks = 0; ks < 8; ++ks) {
            f16x8 afr = *(const f16x8*)&sT[(wave * 16 + lc) * SDT + ks * 32 + lg * 8];
            acc = __builtin_amdgcn_mfma_f32_16x16x32_f16(afr, wreg[ks], acc, 0, 0, 0);
        }
        #pragma unroll
        for (int r = 0; r < 4; ++r) {
            int row = wave * 16 + lg * 4 + r;
            float mask = node_mask[b * NN + row];
            out[((size_t)b * NN + row) * NF + lc] = (acc[r] + bout[lc]) * mask;
        }
    }
}

extern "C" void kernel_launch(void* const* d_in, const int* in_sizes, int n_in,
                              void* d_out, int out_size, void* d_ws, size_t ws_size,
                              hipStream_t stream) {
    const float* x    = (const float*)d_in[0];
    const float* adj  = (const float*)d_in[1];
    const float* mask = (const float*)d_in[2];
    const float* Ws   = (const float*)d_in[3];
    const float* bsp  = (const float*)d_in[4];
    const float* Wout = (const float*)d_in[5];
    const float* bout = (const float*)d_in[6];

    f16* Wt    = (f16*)d_ws;                       // 3*256*256 f16 = 384KB
    f16* WoutT = Wt + NL * ND * ND;                // 16*256 f16 = 8KB

    prep_kernel<<<768, 256, 0, stream>>>(Ws, Wout, Wt, WoutT);
    hgcn_kernel<<<NB, 1024, 0, stream>>>(x, adj, mask, Wt, bsp, WoutT, bout,
                                         (float*)d_out);
}